// Round 10
// baseline (111.257 us; speedup 1.0000x reference)
//
#include <hip/hip_runtime.h>

constexpr int NN    = 100000;
constexpr int NE    = 1200000;

constexpr int NBUK = 196;                 // coarse bucket = dst >> 9
constexpr int PB   = 256;                 // pass-1 blocks
constexpr int EPB  = (NE + PB - 1) / PB;  // 4688 edges / p1 block
constexpr int MAT  = NBUK * PB;           // 50176
constexpr int NBM  = (NN + 63) / 64;      // 1563 mfma1 tiles

typedef float  f32x4 __attribute__((ext_vector_type(4)));
typedef short  s16x8 __attribute__((ext_vector_type(8)));

static __device__ __forceinline__ unsigned short f2b(float f) {
    unsigned int u = __float_as_uint(f);
    u = (u + 0x7FFFu + ((u >> 16) & 1u)) >> 16;   // RNE
    return (unsigned short)u;
}
static __device__ __forceinline__ float blo(unsigned int v) {
    return __uint_as_float(v << 16);
}
static __device__ __forceinline__ float bhi(unsigned int v) {
    return __uint_as_float(v & 0xFFFF0000u);
}

// ========== dispatch 1: per-block coarse histogram ==========
__global__ __launch_bounds__(256) void k_p1hist(const int* __restrict__ dst,
                                                int* __restrict__ mat) {
    __shared__ int h[NBUK];
    const int t = threadIdx.x, blk = blockIdx.x;
    for (int i = t; i < NBUK; i += 256) h[i] = 0;
    __syncthreads();
    int beg4 = blk * (EPB / 4);
    int end4 = beg4 + EPB / 4;
    if (end4 > NE / 4) end4 = NE / 4;
    for (int i = beg4 + t; i < end4; i += 256) {
        const int4 d = ((const int4*)dst)[i];
        atomicAdd(&h[d.x >> 9], 1);
        atomicAdd(&h[d.y >> 9], 1);
        atomicAdd(&h[d.z >> 9], 1);
        atomicAdd(&h[d.w >> 9], 1);
    }
    __syncthreads();
    for (int b = t; b < NBUK; b += 256) mat[b * PB + blk] = h[b];
}

// ========== dispatch 2: fused matrix scan (self-computed bucket base) ========
__global__ __launch_bounds__(256) void k_scanAB(const int* __restrict__ mat,
                                                int* __restrict__ matX) {
    __shared__ int lds[256];
    const int bb = blockIdx.x, tid = threadIdx.x;
    // base = total of all previous bucket rows (column-sum, coalesced)
    int part = 0;
    int r = 0;
    for (; r + 3 < bb; r += 4)
        part += mat[r * 256 + tid] + mat[(r + 1) * 256 + tid]
              + mat[(r + 2) * 256 + tid] + mat[(r + 3) * 256 + tid];
    for (; r < bb; ++r) part += mat[r * 256 + tid];
    lds[tid] = part;
    __syncthreads();
    for (int w = 128; w > 0; w >>= 1) {
        if (tid < w) lds[tid] += lds[tid + w];
        __syncthreads();
    }
    const int base = lds[0];
    __syncthreads();
    // row inclusive scan
    int v = mat[bb * 256 + tid];
    lds[tid] = v;
    __syncthreads();
    for (int d = 1; d < 256; d <<= 1) {
        int x = (tid >= d) ? lds[tid - d] : 0;
        __syncthreads();
        lds[tid] += x;
        __syncthreads();
    }
    matX[bb * 256 + tid] = base + lds[tid] - v;   // global exclusive
    if (bb == 0 && tid == 0) matX[MAT] = NE;
}

// ========== dispatch 3: placement into reserved runs ==========
__global__ __launch_bounds__(256) void k_p1place(const int* __restrict__ src,
                                                 const int* __restrict__ dst,
                                                 const int* __restrict__ matX,
                                                 unsigned int* __restrict__ P) {
    __shared__ int cur[NBUK];
    const int t = threadIdx.x, blk = blockIdx.x;
    for (int b = t; b < NBUK; b += 256) cur[b] = matX[b * PB + blk];
    __syncthreads();
    int beg4 = blk * (EPB / 4);
    int end4 = beg4 + EPB / 4;
    if (end4 > NE / 4) end4 = NE / 4;
    for (int i = beg4 + t; i < end4; i += 256) {
        const int4 d = ((const int4*)dst)[i];
        const int4 s = ((const int4*)src)[i];
        int p0 = atomicAdd(&cur[d.x >> 9], 1);
        int p1 = atomicAdd(&cur[d.y >> 9], 1);
        int p2 = atomicAdd(&cur[d.z >> 9], 1);
        int p3 = atomicAdd(&cur[d.w >> 9], 1);
        P[p0] = (unsigned)s.x | ((unsigned)(d.x & 511) << 17);
        P[p1] = (unsigned)s.y | ((unsigned)(d.y & 511) << 17);
        P[p2] = (unsigned)s.z | ((unsigned)(d.z & 511) << 17);
        P[p3] = (unsigned)s.w | ((unsigned)(d.w & 511) << 17);
    }
}

// ========== dispatch 4: pass-2 LDS counting sort (blocks 0..195) + ALL mfma1 ==
__global__ __launch_bounds__(256) void k_sort2_mfma1(const unsigned int* __restrict__ P,
                                                     const int* __restrict__ matX,
                                                     int* __restrict__ esrc,
                                                     int* __restrict__ off,
                                                     const float* __restrict__ feat,
                                                     const float* __restrict__ Ws,
                                                     const float* __restrict__ Wn,
                                                     const float* __restrict__ b,
                                                     unsigned short* __restrict__ C1) {
    __shared__ char smem[16384];
    const int tid = threadIdx.x;

    if (blockIdx.x < NBUK) {
        // ---- sort role ----
        const int bb = blockIdx.x;
        int* cnt = (int*)smem;            // [512] counts, later cursor
        int* sA  = (int*)(smem + 2048);   // [512]
        int* sB  = (int*)(smem + 4096);   // [512]
        const int beg = matX[bb * PB];
        const int end = matX[(bb + 1) * PB];

        for (int i = tid; i < 512; i += 256) cnt[i] = 0;
        __syncthreads();
        for (int i = beg + tid; i < end; i += 256)
            atomicAdd(&cnt[P[i] >> 17], 1);
        __syncthreads();
        for (int i = tid; i < 512; i += 256) sA[i] = cnt[i];
        __syncthreads();
        int* pin = sA; int* pout = sB;
        for (int d = 1; d < 512; d <<= 1) {
            for (int i = tid; i < 512; i += 256)
                pout[i] = pin[i] + (i >= d ? pin[i - d] : 0);
            __syncthreads();
            int* tmp = pin; pin = pout; pout = tmp;
        }
        const int nodes = (bb == NBUK - 1) ? (NN - (NBUK - 1) * 512) : 512;
        for (int i = tid; i < 512; i += 256) {
            int ex = i ? pin[i - 1] : 0;
            cnt[i] = ex;
            if (i < nodes) off[bb * 512 + i] = beg + ex;
        }
        if (bb == NBUK - 1 && tid == 0) off[NN] = NE;
        __syncthreads();
        for (int i = beg + tid; i < end; i += 256) {
            unsigned v = P[i];
            int dl = (int)(v >> 17);
            int pos = atomicAdd(&cnt[dl], 1);
            esrc[beg + pos] = (int)(v & 0x1FFFFu);
        }
        return;
    }

    // ---- mfma1 role ----
    unsigned short* Bl = (unsigned short*)smem;  // [16*64*8] 16KB
    const int mid = blockIdx.x - NBUK;

    for (int idx = tid; idx < 16 * 64; idx += 256) {
        int frag = idx >> 6, le = idx & 63;
        int ct = frag >> 1, kt = frag & 1;
        int col = ct * 16 + (le & 15);
        int kb  = kt * 32 + (le >> 4) * 8;
        unsigned short tmp[8];
#pragma unroll
        for (int j = 0; j < 8; ++j) {
            int k = kb + j;
            float w = (col < 64) ? Ws[k * 64 + col] : Wn[k * 64 + (col - 64)];
            tmp[j] = f2b(w);
        }
        uint4 pk;
        pk.x = (unsigned)tmp[0] | ((unsigned)tmp[1] << 16);
        pk.y = (unsigned)tmp[2] | ((unsigned)tmp[3] << 16);
        pk.z = (unsigned)tmp[4] | ((unsigned)tmp[5] << 16);
        pk.w = (unsigned)tmp[6] | ((unsigned)tmp[7] << 16);
        *(uint4*)(&Bl[idx * 8]) = pk;
    }
    __syncthreads();

    const int wave = tid >> 6, lane = tid & 63;
    const int r0 = mid * 64 + wave * 16;

    s16x8 a[2];
#pragma unroll
    for (int kt = 0; kt < 2; ++kt) {
        int row = r0 + (lane & 15);
        if (row >= NN) row = NN - 1;
        int kb = kt * 32 + (lane >> 4) * 8;
        const float4 f0 = *(const float4*)(feat + (size_t)row * 64 + kb);
        const float4 f1 = *(const float4*)(feat + (size_t)row * 64 + kb + 4);
        a[kt][0] = (short)f2b(f0.x); a[kt][1] = (short)f2b(f0.y);
        a[kt][2] = (short)f2b(f0.z); a[kt][3] = (short)f2b(f0.w);
        a[kt][4] = (short)f2b(f1.x); a[kt][5] = (short)f2b(f1.y);
        a[kt][6] = (short)f2b(f1.z); a[kt][7] = (short)f2b(f1.w);
    }

    const s16x8* Bl8 = (const s16x8*)Bl;
#pragma unroll
    for (int ct = 0; ct < 8; ++ct) {
        f32x4 acc = {0.f, 0.f, 0.f, 0.f};
#pragma unroll
        for (int kt = 0; kt < 2; ++kt) {
            s16x8 bf = Bl8[(ct * 2 + kt) * 64 + lane];
            acc = __builtin_amdgcn_mfma_f32_16x16x32_bf16(a[kt], bf, acc, 0, 0, 0);
        }
        int c = ct * 16 + (lane & 15);
        float bias = (c < 64) ? b[c] : 0.f;
#pragma unroll
        for (int q = 0; q < 4; ++q) {
            int r = r0 + (lane >> 4) * 4 + q;
            if (r < NN) C1[(size_t)r * 128 + c] = f2b(acc[q] + bias);
        }
    }
}

// ===== fused: gather-mean layer1 (8 lanes/node, 16B/lane, unroll8)
//       -> LDS h1 tile (swizzled) -> GEMM2 =====
__global__ __launch_bounds__(256) void k_gath1_mfma2(const int* __restrict__ off,
                                                     const int* __restrict__ esrc,
                                                     const unsigned short* __restrict__ C1,
                                                     const float* __restrict__ Ws,
                                                     const float* __restrict__ Wn,
                                                     const float* __restrict__ b,
                                                     float* __restrict__ C2s,
                                                     unsigned short* __restrict__ C2n) {
    __shared__ unsigned short Bl[8 * 64 * 8];  // 8KB weight frags
    __shared__ unsigned short Hl[64 * 64];     // 8KB h1 tile, XOR-swizzled rows
    const int tid = threadIdx.x;

    for (int idx = tid; idx < 8 * 64; idx += 256) {
        int frag = idx >> 6, le = idx & 63;
        int ct = frag >> 1, kt = frag & 1;
        int col = ct * 16 + (le & 15);
        int kb  = kt * 32 + (le >> 4) * 8;
        unsigned short tmp[8];
#pragma unroll
        for (int j = 0; j < 8; ++j) {
            int k = kb + j;
            float w = (col < 32) ? Ws[k * 32 + col] : Wn[k * 32 + (col - 32)];
            tmp[j] = f2b(w);
        }
        uint4 pk;
        pk.x = (unsigned)tmp[0] | ((unsigned)tmp[1] << 16);
        pk.y = (unsigned)tmp[2] | ((unsigned)tmp[3] << 16);
        pk.z = (unsigned)tmp[4] | ((unsigned)tmp[5] << 16);
        pk.w = (unsigned)tmp[6] | ((unsigned)tmp[7] << 16);
        *(uint4*)(&Bl[idx * 8]) = pk;
    }

    const int base = blockIdx.x * 64;
    const int sub = tid & 7;           // 8 lanes/node, 16B each
#pragma unroll 1
    for (int g = 0; g < 2; ++g) {
        int rloc = g * 32 + (tid >> 3);
        int node = base + rloc;
        if (node < NN) {
            int beg = off[node], end = off[node + 1];
            float a0 = 0.f, a1 = 0.f, a2 = 0.f, a3 = 0.f;
            float a4 = 0.f, a5 = 0.f, a6 = 0.f, a7 = 0.f;
            float c0 = 0.f, c1 = 0.f, c2 = 0.f, c3 = 0.f;
            float c4 = 0.f, c5 = 0.f, c6 = 0.f, c7 = 0.f;
            int k = beg;
            for (; k + 7 < end; k += 8) {
                int e0 = esrc[k],     e1 = esrc[k + 1], e2 = esrc[k + 2], e3 = esrc[k + 3];
                int e4 = esrc[k + 4], e5 = esrc[k + 5], e6 = esrc[k + 6], e7 = esrc[k + 7];
                uint4 v0 = *(const uint4*)(C1 + (size_t)e0 * 128 + 64 + sub * 8);
                uint4 v1 = *(const uint4*)(C1 + (size_t)e1 * 128 + 64 + sub * 8);
                uint4 v2 = *(const uint4*)(C1 + (size_t)e2 * 128 + 64 + sub * 8);
                uint4 v3 = *(const uint4*)(C1 + (size_t)e3 * 128 + 64 + sub * 8);
                uint4 v4 = *(const uint4*)(C1 + (size_t)e4 * 128 + 64 + sub * 8);
                uint4 v5 = *(const uint4*)(C1 + (size_t)e5 * 128 + 64 + sub * 8);
                uint4 v6 = *(const uint4*)(C1 + (size_t)e6 * 128 + 64 + sub * 8);
                uint4 v7 = *(const uint4*)(C1 + (size_t)e7 * 128 + 64 + sub * 8);
                a0 += blo(v0.x); a1 += bhi(v0.x); a2 += blo(v0.y); a3 += bhi(v0.y);
                a4 += blo(v0.z); a5 += bhi(v0.z); a6 += blo(v0.w); a7 += bhi(v0.w);
                c0 += blo(v1.x); c1 += bhi(v1.x); c2 += blo(v1.y); c3 += bhi(v1.y);
                c4 += blo(v1.z); c5 += bhi(v1.z); c6 += blo(v1.w); c7 += bhi(v1.w);
                a0 += blo(v2.x); a1 += bhi(v2.x); a2 += blo(v2.y); a3 += bhi(v2.y);
                a4 += blo(v2.z); a5 += bhi(v2.z); a6 += blo(v2.w); a7 += bhi(v2.w);
                c0 += blo(v3.x); c1 += bhi(v3.x); c2 += blo(v3.y); c3 += bhi(v3.y);
                c4 += blo(v3.z); c5 += bhi(v3.z); c6 += blo(v3.w); c7 += bhi(v3.w);
                a0 += blo(v4.x); a1 += bhi(v4.x); a2 += blo(v4.y); a3 += bhi(v4.y);
                a4 += blo(v4.z); a5 += bhi(v4.z); a6 += blo(v4.w); a7 += bhi(v4.w);
                c0 += blo(v5.x); c1 += bhi(v5.x); c2 += blo(v5.y); c3 += bhi(v5.y);
                c4 += blo(v5.z); c5 += bhi(v5.z); c6 += blo(v5.w); c7 += bhi(v5.w);
                a0 += blo(v6.x); a1 += bhi(v6.x); a2 += blo(v6.y); a3 += bhi(v6.y);
                a4 += blo(v6.z); a5 += bhi(v6.z); a6 += blo(v6.w); a7 += bhi(v6.w);
                c0 += blo(v7.x); c1 += bhi(v7.x); c2 += blo(v7.y); c3 += bhi(v7.y);
                c4 += blo(v7.z); c5 += bhi(v7.z); c6 += blo(v7.w); c7 += bhi(v7.w);
            }
            for (; k + 3 < end; k += 4) {
                int e0 = esrc[k], e1 = esrc[k + 1], e2 = esrc[k + 2], e3 = esrc[k + 3];
                uint4 v0 = *(const uint4*)(C1 + (size_t)e0 * 128 + 64 + sub * 8);
                uint4 v1 = *(const uint4*)(C1 + (size_t)e1 * 128 + 64 + sub * 8);
                uint4 v2 = *(const uint4*)(C1 + (size_t)e2 * 128 + 64 + sub * 8);
                uint4 v3 = *(const uint4*)(C1 + (size_t)e3 * 128 + 64 + sub * 8);
                a0 += blo(v0.x); a1 += bhi(v0.x); a2 += blo(v0.y); a3 += bhi(v0.y);
                a4 += blo(v0.z); a5 += bhi(v0.z); a6 += blo(v0.w); a7 += bhi(v0.w);
                c0 += blo(v1.x); c1 += bhi(v1.x); c2 += blo(v1.y); c3 += bhi(v1.y);
                c4 += blo(v1.z); c5 += bhi(v1.z); c6 += blo(v1.w); c7 += bhi(v1.w);
                a0 += blo(v2.x); a1 += bhi(v2.x); a2 += blo(v2.y); a3 += bhi(v2.y);
                a4 += blo(v2.z); a5 += bhi(v2.z); a6 += blo(v2.w); a7 += bhi(v2.w);
                c0 += blo(v3.x); c1 += bhi(v3.x); c2 += blo(v3.y); c3 += bhi(v3.y);
                c4 += blo(v3.z); c5 += bhi(v3.z); c6 += blo(v3.w); c7 += bhi(v3.w);
            }
            for (; k < end; ++k) {
                int e = esrc[k];
                uint4 v = *(const uint4*)(C1 + (size_t)e * 128 + 64 + sub * 8);
                a0 += blo(v.x); a1 += bhi(v.x); a2 += blo(v.y); a3 += bhi(v.y);
                a4 += blo(v.z); a5 += bhi(v.z); a6 += blo(v.w); a7 += bhi(v.w);
            }
            a0 += c0; a1 += c1; a2 += c2; a3 += c3;
            a4 += c4; a5 += c5; a6 += c6; a7 += c7;
            float inv = (end > beg) ? 1.0f / (float)(end - beg) : 0.f;
            uint4 sv = *(const uint4*)(C1 + (size_t)node * 128 + sub * 8);
            uint4 w;
            w.x = (unsigned)f2b(blo(sv.x) + a0 * inv) | ((unsigned)f2b(bhi(sv.x) + a1 * inv) << 16);
            w.y = (unsigned)f2b(blo(sv.y) + a2 * inv) | ((unsigned)f2b(bhi(sv.y) + a3 * inv) << 16);
            w.z = (unsigned)f2b(blo(sv.z) + a4 * inv) | ((unsigned)f2b(bhi(sv.z) + a5 * inv) << 16);
            w.w = (unsigned)f2b(blo(sv.w) + a6 * inv) | ((unsigned)f2b(bhi(sv.w) + a7 * inv) << 16);
            int boff = (rloc * 128 + sub * 16) ^ ((rloc & 7) << 4);
            *(uint4*)((char*)Hl + boff) = w;
        }
    }
    __syncthreads();

    const int wave = tid >> 6, lane = tid & 63;
    const int rl = wave * 16 + (lane & 15);

    s16x8 a[2];
#pragma unroll
    for (int kt = 0; kt < 2; ++kt) {
        int boff = rl * 128 + kt * 64 + (lane >> 4) * 16;
        a[kt] = *(const s16x8*)((const char*)Hl + (boff ^ ((rl & 7) << 4)));
    }

    const s16x8* Bl8 = (const s16x8*)Bl;
#pragma unroll
    for (int ct = 0; ct < 4; ++ct) {
        f32x4 acc = {0.f, 0.f, 0.f, 0.f};
#pragma unroll
        for (int kt = 0; kt < 2; ++kt) {
            s16x8 bf = Bl8[(ct * 2 + kt) * 64 + lane];
            acc = __builtin_amdgcn_mfma_f32_16x16x32_bf16(a[kt], bf, acc, 0, 0, 0);
        }
        int c = ct * 16 + (lane & 15);
#pragma unroll
        for (int q = 0; q < 4; ++q) {
            int r = blockIdx.x * 64 + wave * 16 + (lane >> 4) * 4 + q;
            if (r < NN) {
                if (c < 32) C2s[(size_t)r * 32 + c] = acc[q] + b[c];
                else        C2n[(size_t)r * 32 + (c - 32)] = f2b(acc[q]);
            }
        }
    }
}

// ===== gather 2: 4 lanes/node (16B/lane), unroll8; out = C2s + mean(C2n) =====
__global__ __launch_bounds__(256) void k_gath2(const int* __restrict__ off,
                                               const int* __restrict__ esrc,
                                               const float* __restrict__ C2s,
                                               const unsigned short* __restrict__ C2n,
                                               float* __restrict__ out) {
    int node = blockIdx.x * 64 + (threadIdx.x >> 2);
    int sub  = threadIdx.x & 3;
    if (node >= NN) return;
    int beg = off[node], end = off[node + 1];
    float a0 = 0.f, a1 = 0.f, a2 = 0.f, a3 = 0.f;
    float a4 = 0.f, a5 = 0.f, a6 = 0.f, a7 = 0.f;
    float c0 = 0.f, c1 = 0.f, c2 = 0.f, c3 = 0.f;
    float c4 = 0.f, c5 = 0.f, c6 = 0.f, c7 = 0.f;
    int k = beg;
    for (; k + 7 < end; k += 8) {
        int e0 = esrc[k],     e1 = esrc[k + 1], e2 = esrc[k + 2], e3 = esrc[k + 3];
        int e4 = esrc[k + 4], e5 = esrc[k + 5], e6 = esrc[k + 6], e7 = esrc[k + 7];
        uint4 v0 = *(const uint4*)(C2n + (size_t)e0 * 32 + sub * 8);
        uint4 v1 = *(const uint4*)(C2n + (size_t)e1 * 32 + sub * 8);
        uint4 v2 = *(const uint4*)(C2n + (size_t)e2 * 32 + sub * 8);
        uint4 v3 = *(const uint4*)(C2n + (size_t)e3 * 32 + sub * 8);
        uint4 v4 = *(const uint4*)(C2n + (size_t)e4 * 32 + sub * 8);
        uint4 v5 = *(const uint4*)(C2n + (size_t)e5 * 32 + sub * 8);
        uint4 v6 = *(const uint4*)(C2n + (size_t)e6 * 32 + sub * 8);
        uint4 v7 = *(const uint4*)(C2n + (size_t)e7 * 32 + sub * 8);
        a0 += blo(v0.x); a1 += bhi(v0.x); a2 += blo(v0.y); a3 += bhi(v0.y);
        a4 += blo(v0.z); a5 += bhi(v0.z); a6 += blo(v0.w); a7 += bhi(v0.w);
        c0 += blo(v1.x); c1 += bhi(v1.x); c2 += blo(v1.y); c3 += bhi(v1.y);
        c4 += blo(v1.z); c5 += bhi(v1.z); c6 += blo(v1.w); c7 += bhi(v1.w);
        a0 += blo(v2.x); a1 += bhi(v2.x); a2 += blo(v2.y); a3 += bhi(v2.y);
        a4 += blo(v2.z); a5 += bhi(v2.z); a6 += blo(v2.w); a7 += bhi(v2.w);
        c0 += blo(v3.x); c1 += bhi(v3.x); c2 += blo(v3.y); c3 += bhi(v3.y);
        c4 += blo(v3.z); c5 += bhi(v3.z); c6 += blo(v3.w); c7 += bhi(v3.w);
        a0 += blo(v4.x); a1 += bhi(v4.x); a2 += blo(v4.y); a3 += bhi(v4.y);
        a4 += blo(v4.z); a5 += bhi(v4.z); a6 += blo(v4.w); a7 += bhi(v4.w);
        c0 += blo(v5.x); c1 += bhi(v5.x); c2 += blo(v5.y); c3 += bhi(v5.y);
        c4 += blo(v5.z); c5 += bhi(v5.z); c6 += blo(v5.w); c7 += bhi(v5.w);
        a0 += blo(v6.x); a1 += bhi(v6.x); a2 += blo(v6.y); a3 += bhi(v6.y);
        a4 += blo(v6.z); a5 += bhi(v6.z); a6 += blo(v6.w); a7 += bhi(v6.w);
        c0 += blo(v7.x); c1 += bhi(v7.x); c2 += blo(v7.y); c3 += bhi(v7.y);
        c4 += blo(v7.z); c5 += bhi(v7.z); c6 += blo(v7.w); c7 += bhi(v7.w);
    }
    for (; k + 3 < end; k += 4) {
        int e0 = esrc[k], e1 = esrc[k + 1], e2 = esrc[k + 2], e3 = esrc[k + 3];
        uint4 v0 = *(const uint4*)(C2n + (size_t)e0 * 32 + sub * 8);
        uint4 v1 = *(const uint4*)(C2n + (size_t)e1 * 32 + sub * 8);
        uint4 v2 = *(const uint4*)(C2n + (size_t)e2 * 32 + sub * 8);
        uint4 v3 = *(const uint4*)(C2n + (size_t)e3 * 32 + sub * 8);
        a0 += blo(v0.x); a1 += bhi(v0.x); a2 += blo(v0.y); a3 += bhi(v0.y);
        a4 += blo(v0.z); a5 += bhi(v0.z); a6 += blo(v0.w); a7 += bhi(v0.w);
        c0 += blo(v1.x); c1 += bhi(v1.x); c2 += blo(v1.y); c3 += bhi(v1.y);
        c4 += blo(v1.z); c5 += bhi(v1.z); c6 += blo(v1.w); c7 += bhi(v1.w);
        a0 += blo(v2.x); a1 += bhi(v2.x); a2 += blo(v2.y); a3 += bhi(v2.y);
        a4 += blo(v2.z); a5 += bhi(v2.z); a6 += blo(v2.w); a7 += bhi(v2.w);
        c0 += blo(v3.x); c1 += bhi(v3.x); c2 += blo(v3.y); c3 += bhi(v3.y);
        c4 += blo(v3.z); c5 += bhi(v3.z); c6 += blo(v3.w); c7 += bhi(v3.w);
    }
    for (; k < end; ++k) {
        int e = esrc[k];
        uint4 v = *(const uint4*)(C2n + (size_t)e * 32 + sub * 8);
        a0 += blo(v.x); a1 += bhi(v.x); a2 += blo(v.y); a3 += bhi(v.y);
        a4 += blo(v.z); a5 += bhi(v.z); a6 += blo(v.w); a7 += bhi(v.w);
    }
    a0 += c0; a1 += c1; a2 += c2; a3 += c3;
    a4 += c4; a5 += c5; a6 += c6; a7 += c7;
    float inv = (end > beg) ? 1.0f / (float)(end - beg) : 0.f;
    const float4 s0 = *(const float4*)(C2s + (size_t)node * 32 + sub * 8);
    const float4 s1 = *(const float4*)(C2s + (size_t)node * 32 + sub * 8 + 4);
    float4 o0, o1;
    o0.x = s0.x + a0 * inv; o0.y = s0.y + a1 * inv;
    o0.z = s0.z + a2 * inv; o0.w = s0.w + a3 * inv;
    o1.x = s1.x + a4 * inv; o1.y = s1.y + a5 * inv;
    o1.z = s1.z + a6 * inv; o1.w = s1.w + a7 * inv;
    *(float4*)(out + (size_t)node * 32 + sub * 8) = o0;
    *(float4*)(out + (size_t)node * 32 + sub * 8 + 4) = o1;
}

extern "C" void kernel_launch(void* const* d_in, const int* in_sizes, int n_in,
                              void* d_out, int out_size, void* d_ws, size_t ws_size,
                              hipStream_t stream) {
    const float* feat    = (const float*)d_in[0];
    const int*   src     = (const int*)d_in[1];
    const int*   dst     = (const int*)d_in[2];
    const float* Wself1  = (const float*)d_in[3];
    const float* Wneigh1 = (const float*)d_in[4];
    const float* b1      = (const float*)d_in[5];
    const float* Wself2  = (const float*)d_in[6];
    const float* Wneigh2 = (const float*)d_in[7];
    const float* b2      = (const float*)d_in[8];
    float* out = (float*)d_out;

    char* ws = (char*)d_ws;
    size_t offb = 0;
    auto alloc = [&](size_t bytes) -> void* {
        void* p = ws + offb;
        offb += (bytes + 255) & ~(size_t)255;
        return p;
    };
    int*            mat  = (int*)alloc((size_t)MAT * sizeof(int));
    int*            matX = (int*)alloc((size_t)(MAT + 1) * sizeof(int));
    unsigned int*   P    = (unsigned int*)alloc((size_t)NE * sizeof(int));
    int*            esrc = (int*)alloc((size_t)NE * sizeof(int));
    int*            off  = (int*)alloc((size_t)(NN + 1) * sizeof(int));
    unsigned short* C1   = (unsigned short*)alloc((size_t)NN * 128 * 2);
    float*          C2s  = (float*)alloc((size_t)NN * 32 * sizeof(float));
    unsigned short* C2n  = (unsigned short*)alloc((size_t)NN * 32 * 2);

    // ---- CSR build: two-pass LDS counting sort (no global atomics) ----
    k_p1hist<<<PB, 256, 0, stream>>>(dst, mat);
    k_scanAB<<<NBUK, 256, 0, stream>>>(mat, matX);
    k_p1place<<<PB, 256, 0, stream>>>(src, dst, matX, P);

    // ---- pass-2 sort (196 blocks) + layer-1 GEMM (1563 blocks), one dispatch ----
    k_sort2_mfma1<<<NBUK + NBM, 256, 0, stream>>>(P, matX, esrc, off,
                                                  feat, Wself1, Wneigh1, b1, C1);

    // ---- layer-1 gather + layer-2 GEMM fused; then layer-2 gather ----
    k_gath1_mfma2<<<(NN + 63) / 64, 256, 0, stream>>>(off, esrc, C1, Wself2, Wneigh2, b2, C2s, C2n);
    k_gath2<<<(NN + 63) / 64, 256, 0, stream>>>(off, esrc, C2s, C2n, out);
}

// Round 11
// 102.654 us; speedup vs baseline: 1.0838x; 1.0838x over previous
//
#include <hip/hip_runtime.h>

constexpr int NN    = 100000;
constexpr int NE    = 1200000;

constexpr int NBUK = 196;                 // coarse bucket = dst >> 9
constexpr int PB   = 256;                 // pass-1 blocks
constexpr int EPB  = (NE + PB - 1) / PB;  // 4688 edges / p1 block
constexpr int MAT  = NBUK * PB;           // 50176
constexpr int NBM  = (NN + 63) / 64;      // 1563 mfma1 tiles

typedef float  f32x4 __attribute__((ext_vector_type(4)));
typedef short  s16x8 __attribute__((ext_vector_type(8)));

static __device__ __forceinline__ unsigned short f2b(float f) {
    unsigned int u = __float_as_uint(f);
    u = (u + 0x7FFFu + ((u >> 16) & 1u)) >> 16;   // RNE
    return (unsigned short)u;
}
static __device__ __forceinline__ float blo(unsigned int v) {
    return __uint_as_float(v << 16);
}
static __device__ __forceinline__ float bhi(unsigned int v) {
    return __uint_as_float(v & 0xFFFF0000u);
}

// ========== dispatch 1: per-block coarse histogram ==========
__global__ __launch_bounds__(256) void k_p1hist(const int* __restrict__ dst,
                                                int* __restrict__ mat) {
    __shared__ int h[NBUK];
    const int t = threadIdx.x, blk = blockIdx.x;
    for (int i = t; i < NBUK; i += 256) h[i] = 0;
    __syncthreads();
    int beg4 = blk * (EPB / 4);
    int end4 = beg4 + EPB / 4;
    if (end4 > NE / 4) end4 = NE / 4;
    for (int i = beg4 + t; i < end4; i += 256) {
        const int4 d = ((const int4*)dst)[i];
        atomicAdd(&h[d.x >> 9], 1);
        atomicAdd(&h[d.y >> 9], 1);
        atomicAdd(&h[d.z >> 9], 1);
        atomicAdd(&h[d.w >> 9], 1);
    }
    __syncthreads();
    for (int b = t; b < NBUK; b += 256) mat[b * PB + blk] = h[b];
}

// ========== dispatch 2: fused matrix scan (self-computed bucket base) ========
__global__ __launch_bounds__(256) void k_scanAB(const int* __restrict__ mat,
                                                int* __restrict__ matX) {
    __shared__ int lds[256];
    const int bb = blockIdx.x, tid = threadIdx.x;
    // base = total of all previous bucket rows (column-sum, coalesced)
    int part = 0;
    int r = 0;
    for (; r + 3 < bb; r += 4)
        part += mat[r * 256 + tid] + mat[(r + 1) * 256 + tid]
              + mat[(r + 2) * 256 + tid] + mat[(r + 3) * 256 + tid];
    for (; r < bb; ++r) part += mat[r * 256 + tid];
    lds[tid] = part;
    __syncthreads();
    for (int w = 128; w > 0; w >>= 1) {
        if (tid < w) lds[tid] += lds[tid + w];
        __syncthreads();
    }
    const int base = lds[0];
    __syncthreads();
    // row inclusive scan
    int v = mat[bb * 256 + tid];
    lds[tid] = v;
    __syncthreads();
    for (int d = 1; d < 256; d <<= 1) {
        int x = (tid >= d) ? lds[tid - d] : 0;
        __syncthreads();
        lds[tid] += x;
        __syncthreads();
    }
    matX[bb * 256 + tid] = base + lds[tid] - v;   // global exclusive
    if (bb == 0 && tid == 0) matX[MAT] = NE;
}

// ========== dispatch 3: placement into reserved runs ==========
__global__ __launch_bounds__(256) void k_p1place(const int* __restrict__ src,
                                                 const int* __restrict__ dst,
                                                 const int* __restrict__ matX,
                                                 unsigned int* __restrict__ P) {
    __shared__ int cur[NBUK];
    const int t = threadIdx.x, blk = blockIdx.x;
    for (int b = t; b < NBUK; b += 256) cur[b] = matX[b * PB + blk];
    __syncthreads();
    int beg4 = blk * (EPB / 4);
    int end4 = beg4 + EPB / 4;
    if (end4 > NE / 4) end4 = NE / 4;
    for (int i = beg4 + t; i < end4; i += 256) {
        const int4 d = ((const int4*)dst)[i];
        const int4 s = ((const int4*)src)[i];
        int p0 = atomicAdd(&cur[d.x >> 9], 1);
        int p1 = atomicAdd(&cur[d.y >> 9], 1);
        int p2 = atomicAdd(&cur[d.z >> 9], 1);
        int p3 = atomicAdd(&cur[d.w >> 9], 1);
        P[p0] = (unsigned)s.x | ((unsigned)(d.x & 511) << 17);
        P[p1] = (unsigned)s.y | ((unsigned)(d.y & 511) << 17);
        P[p2] = (unsigned)s.z | ((unsigned)(d.z & 511) << 17);
        P[p3] = (unsigned)s.w | ((unsigned)(d.w & 511) << 17);
    }
}

// ========== dispatch 4: pass-2 LDS counting sort (blocks 0..195) + ALL mfma1 ==
__global__ __launch_bounds__(256) void k_sort2_mfma1(const unsigned int* __restrict__ P,
                                                     const int* __restrict__ matX,
                                                     int* __restrict__ esrc,
                                                     int* __restrict__ off,
                                                     const float* __restrict__ feat,
                                                     const float* __restrict__ Ws,
                                                     const float* __restrict__ Wn,
                                                     const float* __restrict__ b,
                                                     unsigned short* __restrict__ C1) {
    __shared__ char smem[16384];
    const int tid = threadIdx.x;

    if (blockIdx.x < NBUK) {
        // ---- sort role ----
        const int bb = blockIdx.x;
        int* cnt = (int*)smem;            // [512] counts, later cursor
        int* sA  = (int*)(smem + 2048);   // [512]
        int* sB  = (int*)(smem + 4096);   // [512]
        const int beg = matX[bb * PB];
        const int end = matX[(bb + 1) * PB];

        for (int i = tid; i < 512; i += 256) cnt[i] = 0;
        __syncthreads();
        for (int i = beg + tid; i < end; i += 256)
            atomicAdd(&cnt[P[i] >> 17], 1);
        __syncthreads();
        for (int i = tid; i < 512; i += 256) sA[i] = cnt[i];
        __syncthreads();
        int* pin = sA; int* pout = sB;
        for (int d = 1; d < 512; d <<= 1) {
            for (int i = tid; i < 512; i += 256)
                pout[i] = pin[i] + (i >= d ? pin[i - d] : 0);
            __syncthreads();
            int* tmp = pin; pin = pout; pout = tmp;
        }
        const int nodes = (bb == NBUK - 1) ? (NN - (NBUK - 1) * 512) : 512;
        for (int i = tid; i < 512; i += 256) {
            int ex = i ? pin[i - 1] : 0;
            cnt[i] = ex;
            if (i < nodes) off[bb * 512 + i] = beg + ex;
        }
        if (bb == NBUK - 1 && tid == 0) off[NN] = NE;
        __syncthreads();
        for (int i = beg + tid; i < end; i += 256) {
            unsigned v = P[i];
            int dl = (int)(v >> 17);
            int pos = atomicAdd(&cnt[dl], 1);
            esrc[beg + pos] = (int)(v & 0x1FFFFu);
        }
        return;
    }

    // ---- mfma1 role ----
    unsigned short* Bl = (unsigned short*)smem;  // [16*64*8] 16KB
    const int mid = blockIdx.x - NBUK;

    for (int idx = tid; idx < 16 * 64; idx += 256) {
        int frag = idx >> 6, le = idx & 63;
        int ct = frag >> 1, kt = frag & 1;
        int col = ct * 16 + (le & 15);
        int kb  = kt * 32 + (le >> 4) * 8;
        unsigned short tmp[8];
#pragma unroll
        for (int j = 0; j < 8; ++j) {
            int k = kb + j;
            float w = (col < 64) ? Ws[k * 64 + col] : Wn[k * 64 + (col - 64)];
            tmp[j] = f2b(w);
        }
        uint4 pk;
        pk.x = (unsigned)tmp[0] | ((unsigned)tmp[1] << 16);
        pk.y = (unsigned)tmp[2] | ((unsigned)tmp[3] << 16);
        pk.z = (unsigned)tmp[4] | ((unsigned)tmp[5] << 16);
        pk.w = (unsigned)tmp[6] | ((unsigned)tmp[7] << 16);
        *(uint4*)(&Bl[idx * 8]) = pk;
    }
    __syncthreads();

    const int wave = tid >> 6, lane = tid & 63;
    const int r0 = mid * 64 + wave * 16;

    s16x8 a[2];
#pragma unroll
    for (int kt = 0; kt < 2; ++kt) {
        int row = r0 + (lane & 15);
        if (row >= NN) row = NN - 1;
        int kb = kt * 32 + (lane >> 4) * 8;
        const float4 f0 = *(const float4*)(feat + (size_t)row * 64 + kb);
        const float4 f1 = *(const float4*)(feat + (size_t)row * 64 + kb + 4);
        a[kt][0] = (short)f2b(f0.x); a[kt][1] = (short)f2b(f0.y);
        a[kt][2] = (short)f2b(f0.z); a[kt][3] = (short)f2b(f0.w);
        a[kt][4] = (short)f2b(f1.x); a[kt][5] = (short)f2b(f1.y);
        a[kt][6] = (short)f2b(f1.z); a[kt][7] = (short)f2b(f1.w);
    }

    const s16x8* Bl8 = (const s16x8*)Bl;
#pragma unroll
    for (int ct = 0; ct < 8; ++ct) {
        f32x4 acc = {0.f, 0.f, 0.f, 0.f};
#pragma unroll
        for (int kt = 0; kt < 2; ++kt) {
            s16x8 bf = Bl8[(ct * 2 + kt) * 64 + lane];
            acc = __builtin_amdgcn_mfma_f32_16x16x32_bf16(a[kt], bf, acc, 0, 0, 0);
        }
        int c = ct * 16 + (lane & 15);
        float bias = (c < 64) ? b[c] : 0.f;
#pragma unroll
        for (int q = 0; q < 4; ++q) {
            int r = r0 + (lane >> 4) * 4 + q;
            if (r < NN) C1[(size_t)r * 128 + c] = f2b(acc[q] + bias);
        }
    }
}

// ===== fused: gather-mean layer1 (8 lanes/node, 16B/lane, unroll4)
//       -> LDS h1 tile (swizzled) -> GEMM2 =====
__global__ __launch_bounds__(256) void k_gath1_mfma2(const int* __restrict__ off,
                                                     const int* __restrict__ esrc,
                                                     const unsigned short* __restrict__ C1,
                                                     const float* __restrict__ Ws,
                                                     const float* __restrict__ Wn,
                                                     const float* __restrict__ b,
                                                     float* __restrict__ C2s,
                                                     unsigned short* __restrict__ C2n) {
    __shared__ unsigned short Bl[8 * 64 * 8];  // 8KB weight frags
    __shared__ unsigned short Hl[64 * 64];     // 8KB h1 tile, XOR-swizzled rows
    const int tid = threadIdx.x;

    for (int idx = tid; idx < 8 * 64; idx += 256) {
        int frag = idx >> 6, le = idx & 63;
        int ct = frag >> 1, kt = frag & 1;
        int col = ct * 16 + (le & 15);
        int kb  = kt * 32 + (le >> 4) * 8;
        unsigned short tmp[8];
#pragma unroll
        for (int j = 0; j < 8; ++j) {
            int k = kb + j;
            float w = (col < 32) ? Ws[k * 32 + col] : Wn[k * 32 + (col - 32)];
            tmp[j] = f2b(w);
        }
        uint4 pk;
        pk.x = (unsigned)tmp[0] | ((unsigned)tmp[1] << 16);
        pk.y = (unsigned)tmp[2] | ((unsigned)tmp[3] << 16);
        pk.z = (unsigned)tmp[4] | ((unsigned)tmp[5] << 16);
        pk.w = (unsigned)tmp[6] | ((unsigned)tmp[7] << 16);
        *(uint4*)(&Bl[idx * 8]) = pk;
    }

    const int base = blockIdx.x * 64;
    const int sub = tid & 7;           // 8 lanes/node, 16B each
#pragma unroll 1
    for (int g = 0; g < 2; ++g) {
        int rloc = g * 32 + (tid >> 3);
        int node = base + rloc;
        if (node < NN) {
            int beg = off[node], end = off[node + 1];
            float a0 = 0.f, a1 = 0.f, a2 = 0.f, a3 = 0.f;
            float a4 = 0.f, a5 = 0.f, a6 = 0.f, a7 = 0.f;
            float c0 = 0.f, c1 = 0.f, c2 = 0.f, c3 = 0.f;
            float c4 = 0.f, c5 = 0.f, c6 = 0.f, c7 = 0.f;
            int k = beg;
            for (; k + 3 < end; k += 4) {
                int e0 = esrc[k], e1 = esrc[k + 1], e2 = esrc[k + 2], e3 = esrc[k + 3];
                uint4 v0 = *(const uint4*)(C1 + (size_t)e0 * 128 + 64 + sub * 8);
                uint4 v1 = *(const uint4*)(C1 + (size_t)e1 * 128 + 64 + sub * 8);
                uint4 v2 = *(const uint4*)(C1 + (size_t)e2 * 128 + 64 + sub * 8);
                uint4 v3 = *(const uint4*)(C1 + (size_t)e3 * 128 + 64 + sub * 8);
                a0 += blo(v0.x); a1 += bhi(v0.x); a2 += blo(v0.y); a3 += bhi(v0.y);
                a4 += blo(v0.z); a5 += bhi(v0.z); a6 += blo(v0.w); a7 += bhi(v0.w);
                c0 += blo(v1.x); c1 += bhi(v1.x); c2 += blo(v1.y); c3 += bhi(v1.y);
                c4 += blo(v1.z); c5 += bhi(v1.z); c6 += blo(v1.w); c7 += bhi(v1.w);
                a0 += blo(v2.x); a1 += bhi(v2.x); a2 += blo(v2.y); a3 += bhi(v2.y);
                a4 += blo(v2.z); a5 += bhi(v2.z); a6 += blo(v2.w); a7 += bhi(v2.w);
                c0 += blo(v3.x); c1 += bhi(v3.x); c2 += blo(v3.y); c3 += bhi(v3.y);
                c4 += blo(v3.z); c5 += bhi(v3.z); c6 += blo(v3.w); c7 += bhi(v3.w);
            }
            for (; k < end; ++k) {
                int e = esrc[k];
                uint4 v = *(const uint4*)(C1 + (size_t)e * 128 + 64 + sub * 8);
                a0 += blo(v.x); a1 += bhi(v.x); a2 += blo(v.y); a3 += bhi(v.y);
                a4 += blo(v.z); a5 += bhi(v.z); a6 += blo(v.w); a7 += bhi(v.w);
            }
            a0 += c0; a1 += c1; a2 += c2; a3 += c3;
            a4 += c4; a5 += c5; a6 += c6; a7 += c7;
            float inv = (end > beg) ? 1.0f / (float)(end - beg) : 0.f;
            uint4 sv = *(const uint4*)(C1 + (size_t)node * 128 + sub * 8);
            uint4 w;
            w.x = (unsigned)f2b(blo(sv.x) + a0 * inv) | ((unsigned)f2b(bhi(sv.x) + a1 * inv) << 16);
            w.y = (unsigned)f2b(blo(sv.y) + a2 * inv) | ((unsigned)f2b(bhi(sv.y) + a3 * inv) << 16);
            w.z = (unsigned)f2b(blo(sv.z) + a4 * inv) | ((unsigned)f2b(bhi(sv.z) + a5 * inv) << 16);
            w.w = (unsigned)f2b(blo(sv.w) + a6 * inv) | ((unsigned)f2b(bhi(sv.w) + a7 * inv) << 16);
            int boff = (rloc * 128 + sub * 16) ^ ((rloc & 7) << 4);
            *(uint4*)((char*)Hl + boff) = w;
        }
    }
    __syncthreads();

    const int wave = tid >> 6, lane = tid & 63;
    const int rl = wave * 16 + (lane & 15);

    s16x8 a[2];
#pragma unroll
    for (int kt = 0; kt < 2; ++kt) {
        int boff = rl * 128 + kt * 64 + (lane >> 4) * 16;
        a[kt] = *(const s16x8*)((const char*)Hl + (boff ^ ((rl & 7) << 4)));
    }

    const s16x8* Bl8 = (const s16x8*)Bl;
#pragma unroll
    for (int ct = 0; ct < 4; ++ct) {
        f32x4 acc = {0.f, 0.f, 0.f, 0.f};
#pragma unroll
        for (int kt = 0; kt < 2; ++kt) {
            s16x8 bf = Bl8[(ct * 2 + kt) * 64 + lane];
            acc = __builtin_amdgcn_mfma_f32_16x16x32_bf16(a[kt], bf, acc, 0, 0, 0);
        }
        int c = ct * 16 + (lane & 15);
#pragma unroll
        for (int q = 0; q < 4; ++q) {
            int r = blockIdx.x * 64 + wave * 16 + (lane >> 4) * 4 + q;
            if (r < NN) {
                if (c < 32) C2s[(size_t)r * 32 + c] = acc[q] + b[c];
                else        C2n[(size_t)r * 32 + (c - 32)] = f2b(acc[q]);
            }
        }
    }
}

// ===== gather 2: 4 lanes/node (16B/lane), unroll4; out = C2s + mean(C2n) =====
__global__ __launch_bounds__(256) void k_gath2(const int* __restrict__ off,
                                               const int* __restrict__ esrc,
                                               const float* __restrict__ C2s,
                                               const unsigned short* __restrict__ C2n,
                                               float* __restrict__ out) {
    int node = blockIdx.x * 64 + (threadIdx.x >> 2);
    int sub  = threadIdx.x & 3;
    if (node >= NN) return;
    int beg = off[node], end = off[node + 1];
    float a0 = 0.f, a1 = 0.f, a2 = 0.f, a3 = 0.f;
    float a4 = 0.f, a5 = 0.f, a6 = 0.f, a7 = 0.f;
    float c0 = 0.f, c1 = 0.f, c2 = 0.f, c3 = 0.f;
    float c4 = 0.f, c5 = 0.f, c6 = 0.f, c7 = 0.f;
    int k = beg;
    for (; k + 3 < end; k += 4) {
        int e0 = esrc[k], e1 = esrc[k + 1], e2 = esrc[k + 2], e3 = esrc[k + 3];
        uint4 v0 = *(const uint4*)(C2n + (size_t)e0 * 32 + sub * 8);
        uint4 v1 = *(const uint4*)(C2n + (size_t)e1 * 32 + sub * 8);
        uint4 v2 = *(const uint4*)(C2n + (size_t)e2 * 32 + sub * 8);
        uint4 v3 = *(const uint4*)(C2n + (size_t)e3 * 32 + sub * 8);
        a0 += blo(v0.x); a1 += bhi(v0.x); a2 += blo(v0.y); a3 += bhi(v0.y);
        a4 += blo(v0.z); a5 += bhi(v0.z); a6 += blo(v0.w); a7 += bhi(v0.w);
        c0 += blo(v1.x); c1 += bhi(v1.x); c2 += blo(v1.y); c3 += bhi(v1.y);
        c4 += blo(v1.z); c5 += bhi(v1.z); c6 += blo(v1.w); c7 += bhi(v1.w);
        a0 += blo(v2.x); a1 += bhi(v2.x); a2 += blo(v2.y); a3 += bhi(v2.y);
        a4 += blo(v2.z); a5 += bhi(v2.z); a6 += blo(v2.w); a7 += bhi(v2.w);
        c0 += blo(v3.x); c1 += bhi(v3.x); c2 += blo(v3.y); c3 += bhi(v3.y);
        c4 += blo(v3.z); c5 += bhi(v3.z); c6 += blo(v3.w); c7 += bhi(v3.w);
    }
    for (; k < end; ++k) {
        int e = esrc[k];
        uint4 v = *(const uint4*)(C2n + (size_t)e * 32 + sub * 8);
        a0 += blo(v.x); a1 += bhi(v.x); a2 += blo(v.y); a3 += bhi(v.y);
        a4 += blo(v.z); a5 += bhi(v.z); a6 += blo(v.w); a7 += bhi(v.w);
    }
    a0 += c0; a1 += c1; a2 += c2; a3 += c3;
    a4 += c4; a5 += c5; a6 += c6; a7 += c7;
    float inv = (end > beg) ? 1.0f / (float)(end - beg) : 0.f;
    const float4 s0 = *(const float4*)(C2s + (size_t)node * 32 + sub * 8);
    const float4 s1 = *(const float4*)(C2s + (size_t)node * 32 + sub * 8 + 4);
    float4 o0, o1;
    o0.x = s0.x + a0 * inv; o0.y = s0.y + a1 * inv;
    o0.z = s0.z + a2 * inv; o0.w = s0.w + a3 * inv;
    o1.x = s1.x + a4 * inv; o1.y = s1.y + a5 * inv;
    o1.z = s1.z + a6 * inv; o1.w = s1.w + a7 * inv;
    *(float4*)(out + (size_t)node * 32 + sub * 8) = o0;
    *(float4*)(out + (size_t)node * 32 + sub * 8 + 4) = o1;
}

extern "C" void kernel_launch(void* const* d_in, const int* in_sizes, int n_in,
                              void* d_out, int out_size, void* d_ws, size_t ws_size,
                              hipStream_t stream) {
    const float* feat    = (const float*)d_in[0];
    const int*   src     = (const int*)d_in[1];
    const int*   dst     = (const int*)d_in[2];
    const float* Wself1  = (const float*)d_in[3];
    const float* Wneigh1 = (const float*)d_in[4];
    const float* b1      = (const float*)d_in[5];
    const float* Wself2  = (const float*)d_in[6];
    const float* Wneigh2 = (const float*)d_in[7];
    const float* b2      = (const float*)d_in[8];
    float* out = (float*)d_out;

    char* ws = (char*)d_ws;
    size_t offb = 0;
    auto alloc = [&](size_t bytes) -> void* {
        void* p = ws + offb;
        offb += (bytes + 255) & ~(size_t)255;
        return p;
    };
    int*            mat  = (int*)alloc((size_t)MAT * sizeof(int));
    int*            matX = (int*)alloc((size_t)(MAT + 1) * sizeof(int));
    unsigned int*   P    = (unsigned int*)alloc((size_t)NE * sizeof(int));
    int*            esrc = (int*)alloc((size_t)NE * sizeof(int));
    int*            off  = (int*)alloc((size_t)(NN + 1) * sizeof(int));
    unsigned short* C1   = (unsigned short*)alloc((size_t)NN * 128 * 2);
    float*          C2s  = (float*)alloc((size_t)NN * 32 * sizeof(float));
    unsigned short* C2n  = (unsigned short*)alloc((size_t)NN * 32 * 2);

    // ---- CSR build: two-pass LDS counting sort (no global atomics) ----
    k_p1hist<<<PB, 256, 0, stream>>>(dst, mat);
    k_scanAB<<<NBUK, 256, 0, stream>>>(mat, matX);
    k_p1place<<<PB, 256, 0, stream>>>(src, dst, matX, P);

    // ---- pass-2 sort (196 blocks) + layer-1 GEMM (1563 blocks), one dispatch ----
    k_sort2_mfma1<<<NBUK + NBM, 256, 0, stream>>>(P, matX, esrc, off,
                                                  feat, Wself1, Wneigh1, b1, C1);

    // ---- layer-1 gather + layer-2 GEMM fused; then layer-2 gather ----
    k_gath1_mfma2<<<(NN + 63) / 64, 256, 0, stream>>>(off, esrc, C1, Wself2, Wneigh2, b2, C2s, C2n);
    k_gath2<<<(NN + 63) / 64, 256, 0, stream>>>(off, esrc, C2s, C2n, out);
}

// Round 12
// 97.135 us; speedup vs baseline: 1.1454x; 1.0568x over previous
//
#include <hip/hip_runtime.h>

constexpr int NN    = 100000;
constexpr int NE    = 1200000;

constexpr int NBUK = 196;                 // coarse bucket = dst >> 9
constexpr int PB   = 256;                 // pass-1 blocks
constexpr int EPB  = (NE + PB - 1) / PB;  // 4688 edges / p1 block
constexpr int MAT  = NBUK * PB;           // 50176
constexpr int NBM  = (NN + 63) / 64;      // 1563 mfma1 tiles

typedef float  f32x4 __attribute__((ext_vector_type(4)));
typedef short  s16x8 __attribute__((ext_vector_type(8)));

static __device__ __forceinline__ unsigned short f2b(float f) {
    unsigned int u = __float_as_uint(f);
    u = (u + 0x7FFFu + ((u >> 16) & 1u)) >> 16;   // RNE
    return (unsigned short)u;
}
static __device__ __forceinline__ float blo(unsigned int v) {
    return __uint_as_float(v << 16);
}
static __device__ __forceinline__ float bhi(unsigned int v) {
    return __uint_as_float(v & 0xFFFF0000u);
}

// ========== pass 1: per-block histogram over 196 coarse buckets ==========
__global__ __launch_bounds__(256) void k_p1hist(const int* __restrict__ dst,
                                                int* __restrict__ mat) {
    __shared__ int h[NBUK];
    const int t = threadIdx.x, blk = blockIdx.x;
    for (int i = t; i < NBUK; i += 256) h[i] = 0;
    __syncthreads();
    int beg4 = blk * (EPB / 4);
    int end4 = beg4 + EPB / 4;
    if (end4 > NE / 4) end4 = NE / 4;
    for (int i = beg4 + t; i < end4; i += 256) {
        const int4 d = ((const int4*)dst)[i];
        atomicAdd(&h[d.x >> 9], 1);
        atomicAdd(&h[d.y >> 9], 1);
        atomicAdd(&h[d.z >> 9], 1);
        atomicAdd(&h[d.w >> 9], 1);
    }
    __syncthreads();
    for (int b = t; b < NBUK; b += 256) mat[b * PB + blk] = h[b];
}

// ===== scanA: per-bucket-row exclusive scan (196 blocks) + row totals T =====
__global__ __launch_bounds__(256) void k_scanA(const int* __restrict__ mat,
                                               int* __restrict__ matX,
                                               int* __restrict__ T) {
    __shared__ int lds[256];
    const int b = blockIdx.x, t = threadIdx.x;
    int v = mat[b * 256 + t];
    lds[t] = v;
    __syncthreads();
    for (int d = 1; d < 256; d <<= 1) {
        int x = (t >= d) ? lds[t - d] : 0;
        __syncthreads();
        lds[t] += x;
        __syncthreads();
    }
    matX[b * 256 + t] = lds[t] - v;          // exclusive within row
    if (t == 255) T[b] = lds[255];
}

// ===== scanB: add bucket base (every block rescans the 196 totals) =====
__global__ __launch_bounds__(256) void k_scanB(const int* __restrict__ T,
                                               int* __restrict__ matX) {
    __shared__ int lds[256];
    const int b = blockIdx.x, t = threadIdx.x;
    lds[t] = (t < NBUK) ? T[t] : 0;
    __syncthreads();
    for (int d = 1; d < 256; d <<= 1) {
        int x = (t >= d) ? lds[t - d] : 0;
        __syncthreads();
        lds[t] += x;
        __syncthreads();
    }
    int base = (b == 0) ? 0 : lds[b - 1];
    matX[b * 256 + t] += base;
    if (b == 0 && t == 0) matX[MAT] = NE;
}

// ========== pass 1 placement: packed (src | dlocal<<17) into reserved runs ====
__global__ __launch_bounds__(256) void k_p1place(const int* __restrict__ src,
                                                 const int* __restrict__ dst,
                                                 const int* __restrict__ matX,
                                                 unsigned int* __restrict__ P) {
    __shared__ int cur[NBUK];
    const int t = threadIdx.x, blk = blockIdx.x;
    for (int b = t; b < NBUK; b += 256) cur[b] = matX[b * PB + blk];
    __syncthreads();
    int beg4 = blk * (EPB / 4);
    int end4 = beg4 + EPB / 4;
    if (end4 > NE / 4) end4 = NE / 4;
    for (int i = beg4 + t; i < end4; i += 256) {
        const int4 d = ((const int4*)dst)[i];
        const int4 s = ((const int4*)src)[i];
        int p0 = atomicAdd(&cur[d.x >> 9], 1);
        int p1 = atomicAdd(&cur[d.y >> 9], 1);
        int p2 = atomicAdd(&cur[d.z >> 9], 1);
        int p3 = atomicAdd(&cur[d.w >> 9], 1);
        P[p0] = (unsigned)s.x | ((unsigned)(d.x & 511) << 17);
        P[p1] = (unsigned)s.y | ((unsigned)(d.y & 511) << 17);
        P[p2] = (unsigned)s.z | ((unsigned)(d.z & 511) << 17);
        P[p3] = (unsigned)s.w | ((unsigned)(d.w & 511) << 17);
    }
}

// ========== merged: pass-2 LDS counting sort (blocks 0..195)  +  GEMM1 ========
__global__ __launch_bounds__(256) void k_sort2_mfma1(const unsigned int* __restrict__ P,
                                                     const int* __restrict__ matX,
                                                     int* __restrict__ esrc,
                                                     int* __restrict__ off,
                                                     const float* __restrict__ feat,
                                                     const float* __restrict__ Ws,
                                                     const float* __restrict__ Wn,
                                                     const float* __restrict__ b,
                                                     unsigned short* __restrict__ C1) {
    __shared__ char smem[16384];
    const int tid = threadIdx.x;

    if (blockIdx.x < NBUK) {
        // ---- sort role ----
        const int bb = blockIdx.x;
        int* cnt = (int*)smem;            // [512] counts, later cursor
        int* sA  = (int*)(smem + 2048);   // [512]
        int* sB  = (int*)(smem + 4096);   // [512]
        const int beg = matX[bb * PB];
        const int end = matX[(bb + 1) * PB];

        for (int i = tid; i < 512; i += 256) cnt[i] = 0;
        __syncthreads();
        for (int i = beg + tid; i < end; i += 256)
            atomicAdd(&cnt[P[i] >> 17], 1);
        __syncthreads();
        for (int i = tid; i < 512; i += 256) sA[i] = cnt[i];
        __syncthreads();
        int* pin = sA; int* pout = sB;
        for (int d = 1; d < 512; d <<= 1) {
            for (int i = tid; i < 512; i += 256)
                pout[i] = pin[i] + (i >= d ? pin[i - d] : 0);
            __syncthreads();
            int* tmp = pin; pin = pout; pout = tmp;
        }
        const int nodes = (bb == NBUK - 1) ? (NN - (NBUK - 1) * 512) : 512;
        for (int i = tid; i < 512; i += 256) {
            int ex = i ? pin[i - 1] : 0;
            cnt[i] = ex;
            if (i < nodes) off[bb * 512 + i] = beg + ex;
        }
        if (bb == NBUK - 1 && tid == 0) off[NN] = NE;
        __syncthreads();
        for (int i = beg + tid; i < end; i += 256) {
            unsigned v = P[i];
            int dl = (int)(v >> 17);
            int pos = atomicAdd(&cnt[dl], 1);
            esrc[beg + pos] = (int)(v & 0x1FFFFu);
        }
        return;
    }

    // ---- mfma1 role ----
    unsigned short* Bl = (unsigned short*)smem;  // [16*64*8] 16KB
    const int mid = blockIdx.x - NBUK;

    for (int idx = tid; idx < 16 * 64; idx += 256) {
        int frag = idx >> 6, le = idx & 63;
        int ct = frag >> 1, kt = frag & 1;
        int col = ct * 16 + (le & 15);
        int kb  = kt * 32 + (le >> 4) * 8;
        unsigned short tmp[8];
#pragma unroll
        for (int j = 0; j < 8; ++j) {
            int k = kb + j;
            float w = (col < 64) ? Ws[k * 64 + col] : Wn[k * 64 + (col - 64)];
            tmp[j] = f2b(w);
        }
        uint4 pk;
        pk.x = (unsigned)tmp[0] | ((unsigned)tmp[1] << 16);
        pk.y = (unsigned)tmp[2] | ((unsigned)tmp[3] << 16);
        pk.z = (unsigned)tmp[4] | ((unsigned)tmp[5] << 16);
        pk.w = (unsigned)tmp[6] | ((unsigned)tmp[7] << 16);
        *(uint4*)(&Bl[idx * 8]) = pk;
    }
    __syncthreads();

    const int wave = tid >> 6, lane = tid & 63;
    const int r0 = mid * 64 + wave * 16;

    s16x8 a[2];
#pragma unroll
    for (int kt = 0; kt < 2; ++kt) {
        int row = r0 + (lane & 15);
        if (row >= NN) row = NN - 1;
        int kb = kt * 32 + (lane >> 4) * 8;
        const float4 f0 = *(const float4*)(feat + (size_t)row * 64 + kb);
        const float4 f1 = *(const float4*)(feat + (size_t)row * 64 + kb + 4);
        a[kt][0] = (short)f2b(f0.x); a[kt][1] = (short)f2b(f0.y);
        a[kt][2] = (short)f2b(f0.z); a[kt][3] = (short)f2b(f0.w);
        a[kt][4] = (short)f2b(f1.x); a[kt][5] = (short)f2b(f1.y);
        a[kt][6] = (short)f2b(f1.z); a[kt][7] = (short)f2b(f1.w);
    }

    const s16x8* Bl8 = (const s16x8*)Bl;
#pragma unroll
    for (int ct = 0; ct < 8; ++ct) {
        f32x4 acc = {0.f, 0.f, 0.f, 0.f};
#pragma unroll
        for (int kt = 0; kt < 2; ++kt) {
            s16x8 bf = Bl8[(ct * 2 + kt) * 64 + lane];
            acc = __builtin_amdgcn_mfma_f32_16x16x32_bf16(a[kt], bf, acc, 0, 0, 0);
        }
        int c = ct * 16 + (lane & 15);
        float bias = (c < 64) ? b[c] : 0.f;
#pragma unroll
        for (int q = 0; q < 4; ++q) {
            int r = r0 + (lane >> 4) * 4 + q;
            if (r < NN) C1[(size_t)r * 128 + c] = f2b(acc[q] + bias);
        }
    }
}

// ===== fused: gather-mean layer1 (8 lanes/node, 16B/lane, unroll4)
//       -> LDS h1 tile (swizzled) -> GEMM2 =====
__global__ __launch_bounds__(256) void k_gath1_mfma2(const int* __restrict__ off,
                                                     const int* __restrict__ esrc,
                                                     const unsigned short* __restrict__ C1,
                                                     const float* __restrict__ Ws,
                                                     const float* __restrict__ Wn,
                                                     const float* __restrict__ b,
                                                     float* __restrict__ C2s,
                                                     unsigned short* __restrict__ C2n) {
    __shared__ unsigned short Bl[8 * 64 * 8];  // 8KB weight frags
    __shared__ unsigned short Hl[64 * 64];     // 8KB h1 tile, XOR-swizzled rows
    const int tid = threadIdx.x;

    for (int idx = tid; idx < 8 * 64; idx += 256) {
        int frag = idx >> 6, le = idx & 63;
        int ct = frag >> 1, kt = frag & 1;
        int col = ct * 16 + (le & 15);
        int kb  = kt * 32 + (le >> 4) * 8;
        unsigned short tmp[8];
#pragma unroll
        for (int j = 0; j < 8; ++j) {
            int k = kb + j;
            float w = (col < 32) ? Ws[k * 32 + col] : Wn[k * 32 + (col - 32)];
            tmp[j] = f2b(w);
        }
        uint4 pk;
        pk.x = (unsigned)tmp[0] | ((unsigned)tmp[1] << 16);
        pk.y = (unsigned)tmp[2] | ((unsigned)tmp[3] << 16);
        pk.z = (unsigned)tmp[4] | ((unsigned)tmp[5] << 16);
        pk.w = (unsigned)tmp[6] | ((unsigned)tmp[7] << 16);
        *(uint4*)(&Bl[idx * 8]) = pk;
    }

    const int base = blockIdx.x * 64;
    const int sub = tid & 7;           // 8 lanes/node, 16B each
#pragma unroll 1
    for (int g = 0; g < 2; ++g) {
        int rloc = g * 32 + (tid >> 3);
        int node = base + rloc;
        if (node < NN) {
            int beg = off[node], end = off[node + 1];
            float a0 = 0.f, a1 = 0.f, a2 = 0.f, a3 = 0.f;
            float a4 = 0.f, a5 = 0.f, a6 = 0.f, a7 = 0.f;
            float c0 = 0.f, c1 = 0.f, c2 = 0.f, c3 = 0.f;
            float c4 = 0.f, c5 = 0.f, c6 = 0.f, c7 = 0.f;
            int k = beg;
            for (; k + 3 < end; k += 4) {
                int e0 = esrc[k], e1 = esrc[k + 1], e2 = esrc[k + 2], e3 = esrc[k + 3];
                uint4 v0 = *(const uint4*)(C1 + (size_t)e0 * 128 + 64 + sub * 8);
                uint4 v1 = *(const uint4*)(C1 + (size_t)e1 * 128 + 64 + sub * 8);
                uint4 v2 = *(const uint4*)(C1 + (size_t)e2 * 128 + 64 + sub * 8);
                uint4 v3 = *(const uint4*)(C1 + (size_t)e3 * 128 + 64 + sub * 8);
                a0 += blo(v0.x); a1 += bhi(v0.x); a2 += blo(v0.y); a3 += bhi(v0.y);
                a4 += blo(v0.z); a5 += bhi(v0.z); a6 += blo(v0.w); a7 += bhi(v0.w);
                c0 += blo(v1.x); c1 += bhi(v1.x); c2 += blo(v1.y); c3 += bhi(v1.y);
                c4 += blo(v1.z); c5 += bhi(v1.z); c6 += blo(v1.w); c7 += bhi(v1.w);
                a0 += blo(v2.x); a1 += bhi(v2.x); a2 += blo(v2.y); a3 += bhi(v2.y);
                a4 += blo(v2.z); a5 += bhi(v2.z); a6 += blo(v2.w); a7 += bhi(v2.w);
                c0 += blo(v3.x); c1 += bhi(v3.x); c2 += blo(v3.y); c3 += bhi(v3.y);
                c4 += blo(v3.z); c5 += bhi(v3.z); c6 += blo(v3.w); c7 += bhi(v3.w);
            }
            for (; k < end; ++k) {
                int e = esrc[k];
                uint4 v = *(const uint4*)(C1 + (size_t)e * 128 + 64 + sub * 8);
                a0 += blo(v.x); a1 += bhi(v.x); a2 += blo(v.y); a3 += bhi(v.y);
                a4 += blo(v.z); a5 += bhi(v.z); a6 += blo(v.w); a7 += bhi(v.w);
            }
            a0 += c0; a1 += c1; a2 += c2; a3 += c3;
            a4 += c4; a5 += c5; a6 += c6; a7 += c7;
            float inv = (end > beg) ? 1.0f / (float)(end - beg) : 0.f;
            uint4 sv = *(const uint4*)(C1 + (size_t)node * 128 + sub * 8);
            uint4 w;
            w.x = (unsigned)f2b(blo(sv.x) + a0 * inv) | ((unsigned)f2b(bhi(sv.x) + a1 * inv) << 16);
            w.y = (unsigned)f2b(blo(sv.y) + a2 * inv) | ((unsigned)f2b(bhi(sv.y) + a3 * inv) << 16);
            w.z = (unsigned)f2b(blo(sv.z) + a4 * inv) | ((unsigned)f2b(bhi(sv.z) + a5 * inv) << 16);
            w.w = (unsigned)f2b(blo(sv.w) + a6 * inv) | ((unsigned)f2b(bhi(sv.w) + a7 * inv) << 16);
            int boff = (rloc * 128 + sub * 16) ^ ((rloc & 7) << 4);
            *(uint4*)((char*)Hl + boff) = w;
        }
    }
    __syncthreads();

    const int wave = tid >> 6, lane = tid & 63;
    const int rl = wave * 16 + (lane & 15);

    s16x8 a[2];
#pragma unroll
    for (int kt = 0; kt < 2; ++kt) {
        int boff = rl * 128 + kt * 64 + (lane >> 4) * 16;
        a[kt] = *(const s16x8*)((const char*)Hl + (boff ^ ((rl & 7) << 4)));
    }

    const s16x8* Bl8 = (const s16x8*)Bl;
#pragma unroll
    for (int ct = 0; ct < 4; ++ct) {
        f32x4 acc = {0.f, 0.f, 0.f, 0.f};
#pragma unroll
        for (int kt = 0; kt < 2; ++kt) {
            s16x8 bf = Bl8[(ct * 2 + kt) * 64 + lane];
            acc = __builtin_amdgcn_mfma_f32_16x16x32_bf16(a[kt], bf, acc, 0, 0, 0);
        }
        int c = ct * 16 + (lane & 15);
#pragma unroll
        for (int q = 0; q < 4; ++q) {
            int r = blockIdx.x * 64 + wave * 16 + (lane >> 4) * 4 + q;
            if (r < NN) {
                if (c < 32) C2s[(size_t)r * 32 + c] = acc[q] + b[c];
                else        C2n[(size_t)r * 32 + (c - 32)] = f2b(acc[q]);
            }
        }
    }
}

// ===== gather 2: 4 lanes/node (16B/lane), unroll4; out = C2s + mean(C2n) =====
__global__ __launch_bounds__(256) void k_gath2(const int* __restrict__ off,
                                               const int* __restrict__ esrc,
                                               const float* __restrict__ C2s,
                                               const unsigned short* __restrict__ C2n,
                                               float* __restrict__ out) {
    int node = blockIdx.x * 64 + (threadIdx.x >> 2);
    int sub  = threadIdx.x & 3;
    if (node >= NN) return;
    int beg = off[node], end = off[node + 1];
    float a0 = 0.f, a1 = 0.f, a2 = 0.f, a3 = 0.f;
    float a4 = 0.f, a5 = 0.f, a6 = 0.f, a7 = 0.f;
    float c0 = 0.f, c1 = 0.f, c2 = 0.f, c3 = 0.f;
    float c4 = 0.f, c5 = 0.f, c6 = 0.f, c7 = 0.f;
    int k = beg;
    for (; k + 3 < end; k += 4) {
        int e0 = esrc[k], e1 = esrc[k + 1], e2 = esrc[k + 2], e3 = esrc[k + 3];
        uint4 v0 = *(const uint4*)(C2n + (size_t)e0 * 32 + sub * 8);
        uint4 v1 = *(const uint4*)(C2n + (size_t)e1 * 32 + sub * 8);
        uint4 v2 = *(const uint4*)(C2n + (size_t)e2 * 32 + sub * 8);
        uint4 v3 = *(const uint4*)(C2n + (size_t)e3 * 32 + sub * 8);
        a0 += blo(v0.x); a1 += bhi(v0.x); a2 += blo(v0.y); a3 += bhi(v0.y);
        a4 += blo(v0.z); a5 += bhi(v0.z); a6 += blo(v0.w); a7 += bhi(v0.w);
        c0 += blo(v1.x); c1 += bhi(v1.x); c2 += blo(v1.y); c3 += bhi(v1.y);
        c4 += blo(v1.z); c5 += bhi(v1.z); c6 += blo(v1.w); c7 += bhi(v1.w);
        a0 += blo(v2.x); a1 += bhi(v2.x); a2 += blo(v2.y); a3 += bhi(v2.y);
        a4 += blo(v2.z); a5 += bhi(v2.z); a6 += blo(v2.w); a7 += bhi(v2.w);
        c0 += blo(v3.x); c1 += bhi(v3.x); c2 += blo(v3.y); c3 += bhi(v3.y);
        c4 += blo(v3.z); c5 += bhi(v3.z); c6 += blo(v3.w); c7 += bhi(v3.w);
    }
    for (; k < end; ++k) {
        int e = esrc[k];
        uint4 v = *(const uint4*)(C2n + (size_t)e * 32 + sub * 8);
        a0 += blo(v.x); a1 += bhi(v.x); a2 += blo(v.y); a3 += bhi(v.y);
        a4 += blo(v.z); a5 += bhi(v.z); a6 += blo(v.w); a7 += bhi(v.w);
    }
    a0 += c0; a1 += c1; a2 += c2; a3 += c3;
    a4 += c4; a5 += c5; a6 += c6; a7 += c7;
    float inv = (end > beg) ? 1.0f / (float)(end - beg) : 0.f;
    const float4 s0 = *(const float4*)(C2s + (size_t)node * 32 + sub * 8);
    const float4 s1 = *(const float4*)(C2s + (size_t)node * 32 + sub * 8 + 4);
    float4 o0, o1;
    o0.x = s0.x + a0 * inv; o0.y = s0.y + a1 * inv;
    o0.z = s0.z + a2 * inv; o0.w = s0.w + a3 * inv;
    o1.x = s1.x + a4 * inv; o1.y = s1.y + a5 * inv;
    o1.z = s1.z + a6 * inv; o1.w = s1.w + a7 * inv;
    *(float4*)(out + (size_t)node * 32 + sub * 8) = o0;
    *(float4*)(out + (size_t)node * 32 + sub * 8 + 4) = o1;
}

extern "C" void kernel_launch(void* const* d_in, const int* in_sizes, int n_in,
                              void* d_out, int out_size, void* d_ws, size_t ws_size,
                              hipStream_t stream) {
    const float* feat    = (const float*)d_in[0];
    const int*   src     = (const int*)d_in[1];
    const int*   dst     = (const int*)d_in[2];
    const float* Wself1  = (const float*)d_in[3];
    const float* Wneigh1 = (const float*)d_in[4];
    const float* b1      = (const float*)d_in[5];
    const float* Wself2  = (const float*)d_in[6];
    const float* Wneigh2 = (const float*)d_in[7];
    const float* b2      = (const float*)d_in[8];
    float* out = (float*)d_out;

    char* ws = (char*)d_ws;
    size_t offb = 0;
    auto alloc = [&](size_t bytes) -> void* {
        void* p = ws + offb;
        offb += (bytes + 255) & ~(size_t)255;
        return p;
    };
    int*            mat  = (int*)alloc((size_t)MAT * sizeof(int));
    int*            matX = (int*)alloc((size_t)(MAT + 1) * sizeof(int));
    int*            T    = (int*)alloc(256 * sizeof(int));
    unsigned int*   P    = (unsigned int*)alloc((size_t)NE * sizeof(int));
    int*            esrc = (int*)alloc((size_t)NE * sizeof(int));
    int*            off  = (int*)alloc((size_t)(NN + 1) * sizeof(int));
    unsigned short* C1   = (unsigned short*)alloc((size_t)NN * 128 * 2);
    float*          C2s  = (float*)alloc((size_t)NN * 32 * sizeof(float));
    unsigned short* C2n  = (unsigned short*)alloc((size_t)NN * 32 * 2);

    // ---- CSR build: two-pass LDS counting sort (no global atomics) ----
    k_p1hist<<<PB, 256, 0, stream>>>(dst, mat);
    k_scanA<<<NBUK, 256, 0, stream>>>(mat, matX, T);
    k_scanB<<<NBUK, 256, 0, stream>>>(T, matX);
    k_p1place<<<PB, 256, 0, stream>>>(src, dst, matX, P);

    // ---- pass-2 sort (196 blocks) + layer-1 GEMM (1563 blocks), one dispatch ----
    k_sort2_mfma1<<<NBUK + NBM, 256, 0, stream>>>(P, matX, esrc, off,
                                                  feat, Wself1, Wneigh1, b1, C1);

    // ---- layer-1 gather + layer-2 GEMM fused; then layer-2 gather ----
    k_gath1_mfma2<<<(NN + 63) / 64, 256, 0, stream>>>(off, esrc, C1, Wself2, Wneigh2, b2, C2s, C2n);
    k_gath2<<<(NN + 63) / 64, 256, 0, stream>>>(off, esrc, C2s, C2n, out);
}